// Round 6
// baseline (215.013 us; speedup 1.0000x reference)
//
#include <hip/hip_runtime.h>
#include <math.h>

#define DD 32
#define MM 16

// ---------- helpers ----------
__device__ __forceinline__ void load8f4(const float* __restrict__ p, float* r) {
    const float4* q = (const float4*)p;
#pragma unroll
    for (int i = 0; i < 8; ++i) {
        float4 v = q[i];
        r[4*i+0] = v.x; r[4*i+1] = v.y; r[4*i+2] = v.z; r[4*i+3] = v.w;
    }
}

__device__ __forceinline__ int mask_len(const unsigned char* __restrict__ mp) {
    uint4 mv = *(const uint4*)mp;
    return __popc(mv.x & 0x01010101u) + __popc(mv.y & 0x01010101u) +
           __popc(mv.z & 0x01010101u) + __popc(mv.w & 0x01010101u);
}

// s = me.t + bb ; fin += s * me
__device__ __forceinline__ void accum(const float* __restrict__ me,
                                      const float* __restrict__ t,
                                      float bb, float* __restrict__ fin) {
    float s = bb;
#pragma unroll
    for (int d = 0; d < DD; ++d) s = fmaf(me[d], t[d], s);
#pragma unroll
    for (int d = 0; d < DD; ++d) fin[d] = fmaf(s, me[d], fin[d]);
}

// ---------- kernel 1: per-item precompute (exact R1 copy, 1 thread/item) ----------
// tbl[i*40 + 0..31] = t_i = W_bil * item_i ; tbl[i*40 + 32..39] = c_i[j] = W1[j,64:96].item_i
__global__ void precompute_item(const float* __restrict__ item_table,
                                const float* __restrict__ W_bil,
                                const float* __restrict__ W1,
                                float* __restrict__ tbl, int NI) {
    int i = blockIdx.x * blockDim.x + threadIdx.x;
    if (i >= NI) return;
    float it[DD];
    load8f4(item_table + (size_t)i * DD, it);
    float* o = tbl + (size_t)i * 40;
#pragma unroll 4
    for (int d = 0; d < DD; ++d) {
        float s = 0.f;
#pragma unroll
        for (int e = 0; e < DD; ++e) s = fmaf(W_bil[d * DD + e], it[e], s);
        o[d] = s;
    }
#pragma unroll
    for (int j = 0; j < 8; ++j) {
        float s = 0.f;
#pragma unroll
        for (int d = 0; d < DD; ++d) s = fmaf(W1[j * 96 + 64 + d], it[d], s);
        o[32 + j] = s;
    }
}

// ---------- kernel 2: main — R1 structure + ping-pong pipelined member loop ----------
__global__ void bilinear_pipe(const int* __restrict__ item_inputs,
                              const int* __restrict__ member_ids,
                              const unsigned char* __restrict__ member_mask,
                              const float* __restrict__ user_table,
                              const float* __restrict__ item_table,
                              const float* __restrict__ tbl,
                              const float* __restrict__ b_bil,
                              const float* __restrict__ W1,
                              const float* __restrict__ b1,
                              const float* __restrict__ W2,
                              const float* __restrict__ b2,
                              float* __restrict__ out, int Btot) {
    int b = blockIdx.x * blockDim.x + threadIdx.x;
    if (b >= Btot) return;

    int item = item_inputs[b];
    int len = mask_len(member_mask + (size_t)b * MM);

    int ids[MM];
    {
        const int4* mp = (const int4*)(member_ids + (size_t)b * MM);
#pragma unroll
        for (int q = 0; q < 4; ++q) {
            int4 v = mp[q];
            ids[4*q+0] = v.x; ids[4*q+1] = v.y; ids[4*q+2] = v.z; ids[4*q+3] = v.w;
        }
    }

    const float* tb = tbl + (size_t)item * 40;
    float t[DD];
    load8f4(tb, t);
    float bb = b_bil[0];

    float fin[DD];
#pragma unroll
    for (int d = 0; d < DD; ++d) fin[d] = 0.f;

    // Ping-pong software pipeline: member m+1's loads issue before computing
    // member m, keeping 8-16 dwordx4 in flight while FMAs run. Rolled loop
    // (small code) — R5 showed the unrolled ladder regresses.
    float cur[DD], nxt[DD];
    load8f4(user_table + (size_t)ids[0] * DD, cur);
    int m = 0;
#pragma unroll 1
    for (; m + 2 <= len; m += 2) {
        load8f4(user_table + (size_t)ids[m + 1] * DD, nxt);
        accum(cur, t, bb, fin);
        if (m + 2 < len) load8f4(user_table + (size_t)ids[m + 2] * DD, cur);
        accum(nxt, t, bb, fin);
    }
    if (m < len) accum(cur, t, bb, fin);   // odd tail (cur preloaded by pipeline)

    float it[DD];
    load8f4(item_table + (size_t)item * DD, it);

    // MLP epilogue (exact R1 form)
    float4 c0 = *(const float4*)(tb + 32);
    float4 c1 = *(const float4*)(tb + 36);
    float h[8] = {c0.x, c0.y, c0.z, c0.w, c1.x, c1.y, c1.z, c1.w};
#pragma unroll
    for (int j = 0; j < 8; ++j) h[j] += b1[j];
#pragma unroll
    for (int d = 0; d < DD; ++d) {
        float f = fin[d];
        float p = f * it[d];
#pragma unroll
        for (int j = 0; j < 8; ++j) {
            h[j] = fmaf(W1[j * 96 + d], p, h[j]);
            h[j] = fmaf(W1[j * 96 + 32 + d], f, h[j]);
        }
    }
    float z = b2[0];
#pragma unroll
    for (int j = 0; j < 8; ++j) {
        float hv = h[j] > 0.f ? h[j] : 0.f;
        z = fmaf(W2[j], hv, z);
    }
    out[b] = 1.f / (1.f + __expf(-z));
}

// ---------- fallback (ws too small): flat 1 thread/row, inline t ----------
__global__ void bilinear_flat(const int* __restrict__ item_inputs,
                              const int* __restrict__ member_ids,
                              const unsigned char* __restrict__ member_mask,
                              const float* __restrict__ user_table,
                              const float* __restrict__ item_table,
                              const float* __restrict__ W_bil,
                              const float* __restrict__ b_bil,
                              const float* __restrict__ W1,
                              const float* __restrict__ b1,
                              const float* __restrict__ W2,
                              const float* __restrict__ b2,
                              float* __restrict__ out, int Btot) {
    int b = blockIdx.x * blockDim.x + threadIdx.x;
    if (b >= Btot) return;
    int item = item_inputs[b];
    int len = mask_len(member_mask + (size_t)b * MM);
    float it0[DD];
    load8f4(item_table + (size_t)item * DD, it0);
    float t[DD];
#pragma unroll 4
    for (int d = 0; d < DD; ++d) {
        float s = 0.f;
#pragma unroll
        for (int e = 0; e < DD; ++e) s = fmaf(W_bil[d * DD + e], it0[e], s);
        t[d] = s;
    }
    float cj[8];
#pragma unroll
    for (int j = 0; j < 8; ++j) {
        float s = 0.f;
#pragma unroll
        for (int d = 0; d < DD; ++d) s = fmaf(W1[j * 96 + 64 + d], it0[d], s);
        cj[j] = s;
    }
    int ids[MM];
    {
        const int4* mp = (const int4*)(member_ids + (size_t)b * MM);
#pragma unroll
        for (int q = 0; q < 4; ++q) {
            int4 v = mp[q];
            ids[4*q+0] = v.x; ids[4*q+1] = v.y; ids[4*q+2] = v.z; ids[4*q+3] = v.w;
        }
    }
    float bb = b_bil[0];
    float fin[DD];
#pragma unroll
    for (int d = 0; d < DD; ++d) fin[d] = 0.f;
#pragma unroll 1
    for (int m = 0; m < len; ++m) {
        float me[DD];
        load8f4(user_table + (size_t)ids[m] * DD, me);
        accum(me, t, bb, fin);
    }
    float h[8] = {cj[0], cj[1], cj[2], cj[3], cj[4], cj[5], cj[6], cj[7]};
#pragma unroll
    for (int j = 0; j < 8; ++j) h[j] += b1[j];
#pragma unroll
    for (int d = 0; d < DD; ++d) {
        float f = fin[d];
        float p = f * it0[d];
#pragma unroll
        for (int j = 0; j < 8; ++j) {
            h[j] = fmaf(W1[j * 96 + d], p, h[j]);
            h[j] = fmaf(W1[j * 96 + 32 + d], f, h[j]);
        }
    }
    float z = b2[0];
#pragma unroll
    for (int j = 0; j < 8; ++j) {
        float hv = h[j] > 0.f ? h[j] : 0.f;
        z = fmaf(W2[j], hv, z);
    }
    out[b] = 1.f / (1.f + __expf(-z));
}

extern "C" void kernel_launch(void* const* d_in, const int* in_sizes, int n_in,
                              void* d_out, int out_size, void* d_ws, size_t ws_size,
                              hipStream_t stream) {
    const int*           item_inputs = (const int*)d_in[0];
    const int*           member_ids  = (const int*)d_in[1];
    const unsigned char* member_mask = (const unsigned char*)d_in[2];
    const float*         user_table  = (const float*)d_in[3];
    const float*         item_table  = (const float*)d_in[4];
    const float*         W_bil       = (const float*)d_in[5];
    const float*         b_bil       = (const float*)d_in[6];
    const float*         W1          = (const float*)d_in[7];
    const float*         b1          = (const float*)d_in[8];
    const float*         W2          = (const float*)d_in[9];
    const float*         b2          = (const float*)d_in[10];
    float* out = (float*)d_out;

    int Btot = in_sizes[0];
    int NI   = in_sizes[4] / DD;

    size_t tbl_bytes = (size_t)NI * 40 * sizeof(float);
    const int blk = 256;
    if (ws_size >= tbl_bytes) {
        float* tbl = (float*)d_ws;
        precompute_item<<<(NI + blk - 1) / blk, blk, 0, stream>>>(item_table, W_bil, W1, tbl, NI);
        bilinear_pipe<<<(Btot + blk - 1) / blk, blk, 0, stream>>>(
            item_inputs, member_ids, member_mask, user_table, item_table, tbl,
            b_bil, W1, b1, W2, b2, out, Btot);
    } else {
        bilinear_flat<<<(Btot + blk - 1) / blk, blk, 0, stream>>>(
            item_inputs, member_ids, member_mask, user_table, item_table,
            W_bil, b_bil, W1, b1, W2, b2, out, Btot);
    }
}